// Round 1
// baseline (1046.339 us; speedup 1.0000x reference)
//
#include <hip/hip_runtime.h>
#include <stdint.h>

// Problem constants
#define N_ROWS 8192
#define D_DIM  1024
#define M_CENT 20000
#define M_PAD  20096          // 157 * 128
#define M_TILES 157
#define Y_DIM  256
#define BM 64                 // rows of X per block
#define BN 128                // centers per M-iteration
#define BK 64                 // K-chunk of D
#define MSPLIT 8
#define TILES_PER_SPLIT 20    // ceil(157/8)
#define LDSP_STRIDE 136       // 128 + 8 pad: breaks bank alignment for P reads/writes

typedef __attribute__((ext_vector_type(4))) float  f32x4;
typedef __attribute__((ext_vector_type(8))) __bf16 bf16x8;

__device__ __forceinline__ unsigned short f2bf(float f) {
    union { float f; unsigned u; } v; v.f = f;
    unsigned u = v.u;
    u += 0x7FFFu + ((u >> 16) & 1u);   // RNE
    return (unsigned short)(u >> 16);
}

// async global->LDS, 16B per lane. LDS dest must be wave-uniform base + lane*16.
__device__ __forceinline__ void gll16(void* lds, const void* g) {
    __builtin_amdgcn_global_load_lds(
        (const __attribute__((address_space(1))) void*)g,
        (__attribute__((address_space(3))) void*)lds, 16, 0, 0);
}

// cast fp32 rows -> bf16, compute fp32 row sum-of-squares; pad rows -> zeros
__global__ void cast_rows_kernel(const float* __restrict__ src,
                                 unsigned short* __restrict__ dst,
                                 float* __restrict__ sq, int nrows_valid) {
    int row = blockIdx.x;
    int t = threadIdx.x;  // 256 threads, 4 floats each = 1024 = D_DIM
    float s = 0.f;
    if (row < nrows_valid) {
        float4 v = ((const float4*)(src + (size_t)row * D_DIM))[t];
        s = v.x * v.x + v.y * v.y + v.z * v.z + v.w * v.w;
        ushort4 o;
        o.x = f2bf(v.x); o.y = f2bf(v.y); o.z = f2bf(v.z); o.w = f2bf(v.w);
        ((ushort4*)(dst + (size_t)row * D_DIM))[t] = o;
    } else {
        ((ushort4*)(dst + (size_t)row * D_DIM))[t] = make_ushort4(0, 0, 0, 0);
    }
    __shared__ float red[4];
    for (int off = 32; off; off >>= 1) s += __shfl_down(s, off, 64);
    if ((t & 63) == 0) red[t >> 6] = s;
    __syncthreads();
    if (t == 0) sq[row] = red[0] + red[1] + red[2] + red[3];
}

// W [M][Y] fp32 -> WT [Y][M_PAD] bf16, pad rows (centers >= M_CENT) -> 0
__global__ void cast_wT_kernel(const float* __restrict__ w,
                               unsigned short* __restrict__ wT) {
    __shared__ float tile[32][33];
    int k0 = blockIdx.x * 32;   // center dim
    int y0 = blockIdx.y * 32;   // Y dim
    int tx = threadIdx.x & 31;
    int ty = threadIdx.x >> 5;  // 0..7
    #pragma unroll
    for (int i = 0; i < 4; ++i) {
        int k = k0 + ty + i * 8;
        float v = (k < M_CENT) ? w[(size_t)k * Y_DIM + y0 + tx] : 0.f;
        tile[tx][ty + i * 8] = v;     // tile[y_local][k_local]
    }
    __syncthreads();
    #pragma unroll
    for (int i = 0; i < 4; ++i) {
        int yl = ty + i * 8;
        wT[(size_t)(y0 + yl) * M_PAD + k0 + tx] = f2bf(tile[yl][tx]);
    }
}

// Fused: per 64-row block and M-range, loop 128-center tiles:
//   S = Xb*Zb^T (MFMA, K=1024), P = exp(-sqrt(max(xsq+zsq-2S,0))/bw) -> LDS bf16,
//   O += P * Wtile (A from LDS, B 16B-frags straight from global WT),
// then atomicAdd O into out.
__global__ void __launch_bounds__(256)
fused_kernel(const unsigned short* __restrict__ Xb,
             const unsigned short* __restrict__ Zb,
             const unsigned short* __restrict__ WbT,
             const float* __restrict__ xsq,
             const float* __restrict__ zsq,
             const int* __restrict__ bwp,
             float* __restrict__ out) {
    __shared__ unsigned short lds_x[BM * BK];          // 8 KB
    __shared__ unsigned short lds_z[BN * BK];          // 16 KB
    __shared__ unsigned short lds_p[BM * LDSP_STRIDE]; // 17 KB (padded, not async-staged)
    __shared__ float lds_xsq[BM];
    __shared__ float lds_zsq[BN];

    const int t    = threadIdx.x;
    const int wave = t >> 6;
    const int lane = t & 63;
    const int quad = lane >> 4;
    const int l16  = lane & 15;

    const int row0 = blockIdx.x * BM;
    int mt = blockIdx.y * TILES_PER_SPLIT;
    int mt_end = mt + TILES_PER_SPLIT;
    if (mt_end > M_TILES) mt_end = M_TILES;

    // bandwidth: int32 per harness convention (Python int 10); tolerate float bits too
    int bwi = *bwp;
    float bw;
    if (bwi > 0 && bwi < 1000000) bw = (float)bwi;
    else { union { int i; float f; } u; u.i = bwi; bw = u.f; }
    const float inv_bw = 1.0f / bw;

    if (t < BM) lds_xsq[t] = xsq[row0 + t];

    const f32x4 vzero = {0.f, 0.f, 0.f, 0.f};
    f32x4 Oacc[16];
    #pragma unroll
    for (int i = 0; i < 16; ++i) Oacc[i] = vzero;

    for (; mt < mt_end; ++mt) {
        const int m0 = mt * BN;
        if (t < BN) lds_zsq[t] = zsq[m0 + t];

        f32x4 S[8];
        #pragma unroll
        for (int i = 0; i < 8; ++i) S[i] = vzero;

        // -------- Phase 1: S = X * Z^T over D --------
        for (int kc = 0; kc < D_DIM / BK; ++kc) {
            const int kbase = kc * BK;
            #pragma unroll
            for (int i = 0; i < 2; ++i) {          // X chunk: 64x64 bf16 = 8KB
                int lin = t + i * 256;             // 16B unit index
                gll16(&lds_x[lin * 8],
                      Xb + (size_t)(row0 + (lin >> 3)) * D_DIM + kbase + (lin & 7) * 8);
            }
            #pragma unroll
            for (int i = 0; i < 4; ++i) {          // Z chunk: 128x64 bf16 = 16KB
                int lin = t + i * 256;
                gll16(&lds_z[lin * 8],
                      Zb + (size_t)(m0 + (lin >> 3)) * D_DIM + kbase + (lin & 7) * 8);
            }
            __syncthreads();                       // drains vmcnt
            #pragma unroll
            for (int kt = 0; kt < 2; ++kt) {
                const int koff = kt * 32 + quad * 8;
                bf16x8 a[4], b[2];
                #pragma unroll
                for (int it = 0; it < 4; ++it)
                    a[it] = *(const bf16x8*)&lds_x[(it * 16 + l16) * BK + koff];
                #pragma unroll
                for (int jt = 0; jt < 2; ++jt)
                    b[jt] = *(const bf16x8*)&lds_z[(wave * 32 + jt * 16 + l16) * BK + koff];
                #pragma unroll
                for (int it = 0; it < 4; ++it)
                    #pragma unroll
                    for (int jt = 0; jt < 2; ++jt)
                        S[it * 2 + jt] = __builtin_amdgcn_mfma_f32_16x16x32_bf16(
                            a[it], b[jt], S[it * 2 + jt], 0, 0, 0);
            }
            __syncthreads();
        }

        // -------- Phase 2: P = exp(-sqrt(d2)/bw) -> lds_p (bf16) --------
        #pragma unroll
        for (int it = 0; it < 4; ++it) {
            #pragma unroll
            for (int jt = 0; jt < 2; ++jt) {
                f32x4 s4 = S[it * 2 + jt];
                const int col = wave * 32 + jt * 16 + l16;
                const float zq = lds_zsq[col];
                #pragma unroll
                for (int r = 0; r < 4; ++r) {
                    const int row = it * 16 + quad * 4 + r;   // C-layout: row=(lane>>4)*4+reg
                    float d2 = lds_xsq[row] + zq - 2.0f * s4[r];
                    d2 = fmaxf(d2, 0.f);
                    float p = __expf(-sqrtf(d2) * inv_bw);
                    lds_p[row * LDSP_STRIDE + col] = f2bf(p);
                }
            }
        }
        __syncthreads();

        // -------- Phase 3: O += P[64x128] * Wtile[128x256] --------
        #pragma unroll
        for (int ks = 0; ks < 4; ++ks) {
            const int koff = ks * 32 + quad * 8;
            bf16x8 a[4], b[4];
            #pragma unroll
            for (int rt = 0; rt < 4; ++rt)
                a[rt] = *(const bf16x8*)&lds_p[(rt * 16 + l16) * LDSP_STRIDE + koff];
            #pragma unroll
            for (int ct = 0; ct < 4; ++ct) {
                const int y = wave * 64 + ct * 16 + l16;
                b[ct] = *(const bf16x8*)(WbT + (size_t)y * M_PAD + m0 + koff);
            }
            #pragma unroll
            for (int rt = 0; rt < 4; ++rt)
                #pragma unroll
                for (int ct = 0; ct < 4; ++ct)
                    Oacc[rt * 4 + ct] = __builtin_amdgcn_mfma_f32_16x16x32_bf16(
                        a[rt], b[ct], Oacc[rt * 4 + ct], 0, 0, 0);
        }
        // no trailing barrier needed: next iter only writes lds_x/z/zsq (not read in Phase 3),
        // and next lds_p write is 32 barriers away.
    }

    // -------- epilogue: accumulate M-splits via device-scope fp32 atomics --------
    #pragma unroll
    for (int rt = 0; rt < 4; ++rt) {
        #pragma unroll
        for (int ct = 0; ct < 4; ++ct) {
            f32x4 v = Oacc[rt * 4 + ct];
            const int y = wave * 64 + ct * 16 + l16;
            #pragma unroll
            for (int r = 0; r < 4; ++r) {
                const int row = row0 + rt * 16 + quad * 4 + r;
                atomicAdd(&out[(size_t)row * Y_DIM + y], v[r]);
            }
        }
    }
}

extern "C" void kernel_launch(void* const* d_in, const int* in_sizes, int n_in,
                              void* d_out, int out_size, void* d_ws, size_t ws_size,
                              hipStream_t stream) {
    const float* X = (const float*)d_in[0];
    const float* Z = (const float*)d_in[1];
    const float* W = (const float*)d_in[2];
    const int*  bw = (const int*)d_in[3];
    float* out = (float*)d_out;

    char* ws = (char*)d_ws;
    size_t off = 0;
    unsigned short* Xb  = (unsigned short*)(ws + off); off += (size_t)N_ROWS * D_DIM * 2;
    unsigned short* Zb  = (unsigned short*)(ws + off); off += (size_t)M_PAD * D_DIM * 2;
    unsigned short* WbT = (unsigned short*)(ws + off); off += (size_t)Y_DIM * M_PAD * 2;
    float* xsq = (float*)(ws + off); off += (size_t)N_ROWS * 4;
    float* zsq = (float*)(ws + off); off += (size_t)M_PAD * 4;
    // total ws use: ~68.3 MB

    hipMemsetAsync(d_out, 0, (size_t)out_size * sizeof(float), stream);
    cast_rows_kernel<<<N_ROWS, 256, 0, stream>>>(X, Xb, xsq, N_ROWS);
    cast_rows_kernel<<<M_PAD, 256, 0, stream>>>(Z, Zb, zsq, M_CENT);
    cast_wT_kernel<<<dim3(M_PAD / 32, Y_DIM / 32), 256, 0, stream>>>(W, WbT);
    fused_kernel<<<dim3(N_ROWS / BM, MSPLIT), 256, 0, stream>>>(Xb, Zb, WbT, xsq, zsq, bw, out);
}

// Round 2
// 997.555 us; speedup vs baseline: 1.0489x; 1.0489x over previous
//
#include <hip/hip_runtime.h>
#include <stdint.h>

// Problem constants
#define N_ROWS 8192
#define D_DIM  1024
#define M_CENT 20000
#define M_PAD  20096          // 157 * 128
#define M_TILES 157
#define Y_DIM  256
#define BM 64                 // rows of X per block
#define BN 128                // centers per M-iteration
#define BK 64                 // K-chunk of D
#define MSPLIT 8
#define TILES_PER_SPLIT 20    // ceil(157/8)
#define LDSP_STRIDE 136       // 128 + 8 pad: P reads hit the 8-cyc floor (17 slots ≡ 1 mod 8)

typedef __attribute__((ext_vector_type(4))) float  f32x4;
typedef __attribute__((ext_vector_type(8))) __bf16 bf16x8;

__device__ __forceinline__ unsigned short f2bf(float f) {
    union { float f; unsigned u; } v; v.f = f;
    unsigned u = v.u;
    u += 0x7FFFu + ((u >> 16) & 1u);   // RNE
    return (unsigned short)(u >> 16);
}

// async global->LDS, 16B per lane. LDS dest must be wave-uniform base + lane*16.
__device__ __forceinline__ void gll16(void* lds, const void* g) {
    __builtin_amdgcn_global_load_lds(
        (const __attribute__((address_space(1))) void*)g,
        (__attribute__((address_space(3))) void*)lds, 16, 0, 0);
}

// cast fp32 rows -> bf16, compute fp32 row sum-of-squares; pad rows -> zeros
__global__ void cast_rows_kernel(const float* __restrict__ src,
                                 unsigned short* __restrict__ dst,
                                 float* __restrict__ sq, int nrows_valid) {
    int row = blockIdx.x;
    int t = threadIdx.x;  // 256 threads, 4 floats each = 1024 = D_DIM
    float s = 0.f;
    if (row < nrows_valid) {
        float4 v = ((const float4*)(src + (size_t)row * D_DIM))[t];
        s = v.x * v.x + v.y * v.y + v.z * v.z + v.w * v.w;
        ushort4 o;
        o.x = f2bf(v.x); o.y = f2bf(v.y); o.z = f2bf(v.z); o.w = f2bf(v.w);
        ((ushort4*)(dst + (size_t)row * D_DIM))[t] = o;
    } else {
        ((ushort4*)(dst + (size_t)row * D_DIM))[t] = make_ushort4(0, 0, 0, 0);
    }
    __shared__ float red[4];
    for (int off = 32; off; off >>= 1) s += __shfl_down(s, off, 64);
    if ((t & 63) == 0) red[t >> 6] = s;
    __syncthreads();
    if (t == 0) sq[row] = red[0] + red[1] + red[2] + red[3];
}

// W [M][Y] fp32 -> WT [Y][M_PAD] bf16, pad rows (centers >= M_CENT) -> 0
__global__ void cast_wT_kernel(const float* __restrict__ w,
                               unsigned short* __restrict__ wT) {
    __shared__ float tile[32][33];
    int k0 = blockIdx.x * 32;   // center dim
    int y0 = blockIdx.y * 32;   // Y dim
    int tx = threadIdx.x & 31;
    int ty = threadIdx.x >> 5;  // 0..7
    #pragma unroll
    for (int i = 0; i < 4; ++i) {
        int k = k0 + ty + i * 8;
        float v = (k < M_CENT) ? w[(size_t)k * Y_DIM + y0 + tx] : 0.f;
        tile[tx][ty + i * 8] = v;     // tile[y_local][k_local]
    }
    __syncthreads();
    #pragma unroll
    for (int i = 0; i < 4; ++i) {
        int yl = ty + i * 8;
        wT[(size_t)(y0 + yl) * M_PAD + k0 + tx] = f2bf(tile[yl][tx]);
    }
}

// Fused flash-style kernel. LDS layout:
//  - lds.s1.x / lds.s1.z hold the Phase-1 staging tiles, XOR-swizzled on the
//    16B-chunk index by (row&7) so frag ds_read_b128s are bank-conflict-free.
//  - lds.p (P matrix, bf16, padded stride) ALIASES x+z: P is only live between
//    the last kc barrier and the end-of-mt barrier, when x/z are dead.
__global__ void __launch_bounds__(256, 4)
fused_kernel(const unsigned short* __restrict__ Xb,
             const unsigned short* __restrict__ Zb,
             const unsigned short* __restrict__ WbT,
             const float* __restrict__ xsq,
             const float* __restrict__ zsq,
             const int* __restrict__ bwp,
             float* __restrict__ out) {
    __shared__ union {
        struct {
            unsigned short x[BM * BK];   // 8 KB
            unsigned short z[BN * BK];   // 16 KB
        } s1;
        unsigned short p[BM * LDSP_STRIDE]; // 17 KB
    } lds;                                  // union: 24 KB -> 4 blocks/CU
    __shared__ float lds_xsq[BM];
    __shared__ float lds_zsq[BN];

    const int t    = threadIdx.x;
    const int wave = t >> 6;
    const int lane = t & 63;
    const int quad = lane >> 4;
    const int l16  = lane & 15;
    const int cx   = l16 & 7;     // row&7 of every frag row this lane touches

    const int row0 = blockIdx.x * BM;
    int mt = blockIdx.y * TILES_PER_SPLIT;
    int mt_end = mt + TILES_PER_SPLIT;
    if (mt_end > M_TILES) mt_end = M_TILES;

    // bandwidth: int32 per harness convention (Python int 10); tolerate float bits too
    int bwi = *bwp;
    float bw;
    if (bwi > 0 && bwi < 1000000) bw = (float)bwi;
    else { union { int i; float f; } u; u.i = bwi; bw = u.f; }
    const float inv_bw = 1.0f / bw;

    if (t < BM) lds_xsq[t] = xsq[row0 + t];

    const f32x4 vzero = {0.f, 0.f, 0.f, 0.f};
    f32x4 Oacc[16];
    #pragma unroll
    for (int i = 0; i < 16; ++i) Oacc[i] = vzero;

    for (; mt < mt_end; ++mt) {
        // protect prev iteration's lds.p reads (Phase 3) from this iteration's
        // staging writes into the aliased x/z region
        __syncthreads();

        const int m0 = mt * BN;
        if (t < BN) lds_zsq[t] = zsq[m0 + t];

        f32x4 S[8];
        #pragma unroll
        for (int i = 0; i < 8; ++i) S[i] = vzero;

        // -------- Phase 1: S = X * Z^T over D --------
        for (int kc = 0; kc < D_DIM / BK; ++kc) {
            const int kbase = kc * BK;
            #pragma unroll
            for (int i = 0; i < 2; ++i) {          // X chunk: 64x64 bf16 = 8KB
                int lin = t + i * 256;             // 16B unit index
                int row = lin >> 3, c = lin & 7;
                gll16(&lds.s1.x[lin * 8],
                      Xb + (size_t)(row0 + row) * D_DIM + kbase + ((c ^ (row & 7)) * 8));
            }
            #pragma unroll
            for (int i = 0; i < 4; ++i) {          // Z chunk: 128x64 bf16 = 16KB
                int lin = t + i * 256;
                int row = lin >> 3, c = lin & 7;
                gll16(&lds.s1.z[lin * 8],
                      Zb + (size_t)(m0 + row) * D_DIM + kbase + ((c ^ (row & 7)) * 8));
            }
            __syncthreads();                       // drains vmcnt
            #pragma unroll
            for (int kt = 0; kt < 2; ++kt) {
                const int sw = ((kt * 4 + quad) ^ cx) * 8;   // swizzled chunk offset
                bf16x8 a[4], b[2];
                #pragma unroll
                for (int it = 0; it < 4; ++it)
                    a[it] = *(const bf16x8*)&lds.s1.x[(it * 16 + l16) * BK + sw];
                #pragma unroll
                for (int jt = 0; jt < 2; ++jt)
                    b[jt] = *(const bf16x8*)&lds.s1.z[(wave * 32 + jt * 16 + l16) * BK + sw];
                #pragma unroll
                for (int it = 0; it < 4; ++it)
                    #pragma unroll
                    for (int jt = 0; jt < 2; ++jt)
                        S[it * 2 + jt] = __builtin_amdgcn_mfma_f32_16x16x32_bf16(
                            a[it], b[jt], S[it * 2 + jt], 0, 0, 0);
            }
            __syncthreads();
        }

        // -------- Phase 2: P = exp(-sqrt(d2)/bw) -> lds.p (bf16) --------
        // x/z tiles are dead now (post-barrier); p aliases them.
        #pragma unroll
        for (int it = 0; it < 4; ++it) {
            #pragma unroll
            for (int jt = 0; jt < 2; ++jt) {
                f32x4 s4 = S[it * 2 + jt];
                const int col = wave * 32 + jt * 16 + l16;
                const float zq = lds_zsq[col];
                #pragma unroll
                for (int r = 0; r < 4; ++r) {
                    const int row = it * 16 + quad * 4 + r;   // C-layout: row=(lane>>4)*4+reg
                    float d2 = lds_xsq[row] + zq - 2.0f * s4[r];
                    d2 = fmaxf(d2, 0.f);
                    float p = __expf(-sqrtf(d2) * inv_bw);
                    lds.p[row * LDSP_STRIDE + col] = f2bf(p);
                }
            }
        }
        __syncthreads();

        // -------- Phase 3: O += P[64x128] * Wtile[128x256] --------
        #pragma unroll
        for (int ks = 0; ks < 4; ++ks) {
            const int koff = ks * 32 + quad * 8;
            bf16x8 a[4], b[4];
            #pragma unroll
            for (int rt = 0; rt < 4; ++rt)
                a[rt] = *(const bf16x8*)&lds.p[(rt * 16 + l16) * LDSP_STRIDE + koff];
            #pragma unroll
            for (int ct = 0; ct < 4; ++ct) {
                const int y = wave * 64 + ct * 16 + l16;
                b[ct] = *(const bf16x8*)(WbT + (size_t)y * M_PAD + m0 + koff);
            }
            #pragma unroll
            for (int rt = 0; rt < 4; ++rt)
                #pragma unroll
                for (int ct = 0; ct < 4; ++ct)
                    Oacc[rt * 4 + ct] = __builtin_amdgcn_mfma_f32_16x16x32_bf16(
                        a[rt], b[ct], Oacc[rt * 4 + ct], 0, 0, 0);
        }
    }

    // -------- epilogue: accumulate M-splits via device-scope fp32 atomics --------
    #pragma unroll
    for (int rt = 0; rt < 4; ++rt) {
        #pragma unroll
        for (int ct = 0; ct < 4; ++ct) {
            f32x4 v = Oacc[rt * 4 + ct];
            const int y = wave * 64 + ct * 16 + l16;
            #pragma unroll
            for (int r = 0; r < 4; ++r) {
                const int row = row0 + rt * 16 + quad * 4 + r;
                atomicAdd(&out[(size_t)row * Y_DIM + y], v[r]);
            }
        }
    }
}

extern "C" void kernel_launch(void* const* d_in, const int* in_sizes, int n_in,
                              void* d_out, int out_size, void* d_ws, size_t ws_size,
                              hipStream_t stream) {
    const float* X = (const float*)d_in[0];
    const float* Z = (const float*)d_in[1];
    const float* W = (const float*)d_in[2];
    const int*  bw = (const int*)d_in[3];
    float* out = (float*)d_out;

    char* ws = (char*)d_ws;
    size_t off = 0;
    unsigned short* Xb  = (unsigned short*)(ws + off); off += (size_t)N_ROWS * D_DIM * 2;
    unsigned short* Zb  = (unsigned short*)(ws + off); off += (size_t)M_PAD * D_DIM * 2;
    unsigned short* WbT = (unsigned short*)(ws + off); off += (size_t)Y_DIM * M_PAD * 2;
    float* xsq = (float*)(ws + off); off += (size_t)N_ROWS * 4;
    float* zsq = (float*)(ws + off); off += (size_t)M_PAD * 4;
    // total ws use: ~68.3 MB

    hipMemsetAsync(d_out, 0, (size_t)out_size * sizeof(float), stream);
    cast_rows_kernel<<<N_ROWS, 256, 0, stream>>>(X, Xb, xsq, N_ROWS);
    cast_rows_kernel<<<M_PAD, 256, 0, stream>>>(Z, Zb, zsq, M_CENT);
    cast_wT_kernel<<<dim3(M_PAD / 32, Y_DIM / 32), 256, 0, stream>>>(W, WbT);
    fused_kernel<<<dim3(N_ROWS / BM, MSPLIT), 256, 0, stream>>>(Xb, Zb, WbT, xsq, zsq, bw, out);
}

// Round 3
// 745.964 us; speedup vs baseline: 1.4027x; 1.3373x over previous
//
#include <hip/hip_runtime.h>
#include <stdint.h>

// Problem constants
#define N_ROWS 8192
#define D_DIM  1024
#define M_CENT 20000
#define M_PAD  20224          // 79 * 256
#define M_TILES 79            // 256-wide center tiles
#define Y_DIM  256
#define BM 64                 // rows of X per block
#define BN 256                // centers per M-iteration (wave tile 64x64)
#define BK 64                 // K-chunk of D
#define MSPLIT 8
#define TILES_PER_SPLIT 10    // ceil(79/8)
#define LDSP_STRIDE 264       // 256 + 8 pad: 33 16B-slots/row ≡ 1 mod 8 -> conflict-free

typedef __attribute__((ext_vector_type(4))) float  f32x4;
typedef __attribute__((ext_vector_type(8))) __bf16 bf16x8;

__device__ __forceinline__ unsigned short f2bf(float f) {
    union { float f; unsigned u; } v; v.f = f;
    unsigned u = v.u;
    u += 0x7FFFu + ((u >> 16) & 1u);   // RNE
    return (unsigned short)(u >> 16);
}

// async global->LDS, 16B per lane. LDS dest must be wave-uniform base + lane*16.
__device__ __forceinline__ void gll16(void* lds, const void* g) {
    __builtin_amdgcn_global_load_lds(
        (const __attribute__((address_space(1))) void*)g,
        (__attribute__((address_space(3))) void*)lds, 16, 0, 0);
}

// cast fp32 rows -> bf16, compute fp32 row sum-of-squares; pad rows -> zeros
__global__ void cast_rows_kernel(const float* __restrict__ src,
                                 unsigned short* __restrict__ dst,
                                 float* __restrict__ sq, int nrows_valid) {
    int row = blockIdx.x;
    int t = threadIdx.x;  // 256 threads, 4 floats each = 1024 = D_DIM
    float s = 0.f;
    if (row < nrows_valid) {
        float4 v = ((const float4*)(src + (size_t)row * D_DIM))[t];
        s = v.x * v.x + v.y * v.y + v.z * v.z + v.w * v.w;
        ushort4 o;
        o.x = f2bf(v.x); o.y = f2bf(v.y); o.z = f2bf(v.z); o.w = f2bf(v.w);
        ((ushort4*)(dst + (size_t)row * D_DIM))[t] = o;
    } else {
        ((ushort4*)(dst + (size_t)row * D_DIM))[t] = make_ushort4(0, 0, 0, 0);
    }
    __shared__ float red[4];
    for (int off = 32; off; off >>= 1) s += __shfl_down(s, off, 64);
    if ((t & 63) == 0) red[t >> 6] = s;
    __syncthreads();
    if (t == 0) sq[row] = red[0] + red[1] + red[2] + red[3];
}

// W [M][Y] fp32 -> WT [Y][M_PAD] bf16, pad rows (centers >= M_CENT) -> 0
__global__ void cast_wT_kernel(const float* __restrict__ w,
                               unsigned short* __restrict__ wT) {
    __shared__ float tile[32][33];
    int k0 = blockIdx.x * 32;   // center dim
    int y0 = blockIdx.y * 32;   // Y dim
    int tx = threadIdx.x & 31;
    int ty = threadIdx.x >> 5;  // 0..7
    #pragma unroll
    for (int i = 0; i < 4; ++i) {
        int k = k0 + ty + i * 8;
        float v = (k < M_CENT) ? w[(size_t)k * Y_DIM + y0 + tx] : 0.f;
        tile[tx][ty + i * 8] = v;     // tile[y_local][k_local]
    }
    __syncthreads();
    #pragma unroll
    for (int i = 0; i < 4; ++i) {
        int yl = ty + i * 8;
        wT[(size_t)(y0 + yl) * M_PAD + k0 + tx] = f2bf(tile[yl][tx]);
    }
}

// Fused flash-style kernel, wave tile 64x64 (4 waves -> 64x256 S per block).
//  - lds.s1.x / lds.s1.z: Phase-1 staging, XOR-swizzled on 16B-chunk index by
//    (row&7) -> frag ds_read_b128s conflict-free (verified R2: 1.9e8 -> 5e6).
//  - lds.p aliases x+z (live ranges disjoint across barriers).
//  - launch_bounds(256,2): ~200 unified regs/wave MUST NOT spill (R2 lesson:
//    forcing 4 waves/EU spilled 2.2 GB/dispatch to scratch).
__global__ void __launch_bounds__(256, 2)
fused_kernel(const unsigned short* __restrict__ Xb,
             const unsigned short* __restrict__ Zb,
             const unsigned short* __restrict__ WbT,
             const float* __restrict__ xsq,
             const float* __restrict__ zsq,
             const int* __restrict__ bwp,
             float* __restrict__ out) {
    __shared__ union {
        struct {
            unsigned short x[BM * BK];   // 8 KB
            unsigned short z[BN * BK];   // 32 KB
        } s1;
        unsigned short p[BM * LDSP_STRIDE]; // 33.8 KB
    } lds;                                  // union: 40 KB -> LDS allows >=2 blocks/CU
    __shared__ float lds_xsq[BM];
    __shared__ float lds_zsq[BN];

    const int t    = threadIdx.x;
    const int wave = t >> 6;
    const int lane = t & 63;
    const int quad = lane >> 4;
    const int l16  = lane & 15;
    const int cx   = l16 & 7;     // row&7 of every frag row this lane touches

    const int row0 = blockIdx.x * BM;
    int mt = blockIdx.y * TILES_PER_SPLIT;
    int mt_end = mt + TILES_PER_SPLIT;
    if (mt_end > M_TILES) mt_end = M_TILES;

    // bandwidth: int32 per harness convention (Python int 10); tolerate float bits too
    int bwi = *bwp;
    float bw;
    if (bwi > 0 && bwi < 1000000) bw = (float)bwi;
    else { union { int i; float f; } u; u.i = bwi; bw = u.f; }
    const float inv_bw = 1.0f / bw;

    if (t < BM) lds_xsq[t] = xsq[row0 + t];

    const f32x4 vzero = {0.f, 0.f, 0.f, 0.f};
    f32x4 Oacc[16];
    #pragma unroll
    for (int i = 0; i < 16; ++i) Oacc[i] = vzero;

    for (; mt < mt_end; ++mt) {
        // protect prev iteration's lds.p reads (Phase 3) from this iteration's
        // staging writes into the aliased x/z region
        __syncthreads();

        const int m0 = mt * BN;
        lds_zsq[t] = zsq[m0 + t];   // BN == blockDim.x == 256

        f32x4 S[16];
        #pragma unroll
        for (int i = 0; i < 16; ++i) S[i] = vzero;

        // -------- Phase 1: S[64x256] = X * Z^T over D --------
        for (int kc = 0; kc < D_DIM / BK; ++kc) {
            const int kbase = kc * BK;
            #pragma unroll
            for (int i = 0; i < 2; ++i) {          // X chunk: 64x64 bf16 = 8KB
                int lin = t + i * 256;             // 16B unit index
                int row = lin >> 3, c = lin & 7;
                gll16(&lds.s1.x[lin * 8],
                      Xb + (size_t)(row0 + row) * D_DIM + kbase + ((c ^ (row & 7)) * 8));
            }
            #pragma unroll
            for (int i = 0; i < 8; ++i) {          // Z chunk: 256x64 bf16 = 32KB
                int lin = t + i * 256;
                int row = lin >> 3, c = lin & 7;
                gll16(&lds.s1.z[lin * 8],
                      Zb + (size_t)(m0 + row) * D_DIM + kbase + ((c ^ (row & 7)) * 8));
            }
            __syncthreads();                       // drains vmcnt
            #pragma unroll
            for (int kt = 0; kt < 2; ++kt) {
                const int sw = ((kt * 4 + quad) ^ cx) * 8;   // swizzled chunk offset
                bf16x8 a[4], b[4];
                #pragma unroll
                for (int it = 0; it < 4; ++it)
                    a[it] = *(const bf16x8*)&lds.s1.x[(it * 16 + l16) * BK + sw];
                #pragma unroll
                for (int jt = 0; jt < 4; ++jt)
                    b[jt] = *(const bf16x8*)&lds.s1.z[(wave * 64 + jt * 16 + l16) * BK + sw];
                #pragma unroll
                for (int it = 0; it < 4; ++it)
                    #pragma unroll
                    for (int jt = 0; jt < 4; ++jt)
                        S[it * 4 + jt] = __builtin_amdgcn_mfma_f32_16x16x32_bf16(
                            a[it], b[jt], S[it * 4 + jt], 0, 0, 0);
            }
            __syncthreads();
        }

        // -------- Phase 2: P = exp(-sqrt(d2)/bw) -> lds.p (bf16) --------
        // x/z tiles are dead now (post-barrier); p aliases them.
        #pragma unroll
        for (int it = 0; it < 4; ++it) {
            #pragma unroll
            for (int jt = 0; jt < 4; ++jt) {
                f32x4 s4 = S[it * 4 + jt];
                const int col = wave * 64 + jt * 16 + l16;
                const float zq = lds_zsq[col];
                #pragma unroll
                for (int r = 0; r < 4; ++r) {
                    const int row = it * 16 + quad * 4 + r;   // C-layout: row=(lane>>4)*4+reg
                    float d2 = lds_xsq[row] + zq - 2.0f * s4[r];
                    d2 = fmaxf(d2, 0.f);
                    float p = __expf(-sqrtf(d2) * inv_bw);
                    lds.p[row * LDSP_STRIDE + col] = f2bf(p);
                }
            }
        }
        __syncthreads();

        // -------- Phase 3: O += P[64x256] * Wtile[256x256] --------
        #pragma unroll
        for (int ks = 0; ks < 8; ++ks) {
            const int koff = ks * 32 + quad * 8;
            bf16x8 a[4], b[4];
            #pragma unroll
            for (int rt = 0; rt < 4; ++rt)
                a[rt] = *(const bf16x8*)&lds.p[(rt * 16 + l16) * LDSP_STRIDE + koff];
            #pragma unroll
            for (int ct = 0; ct < 4; ++ct) {
                const int y = wave * 64 + ct * 16 + l16;
                b[ct] = *(const bf16x8*)(WbT + (size_t)y * M_PAD + m0 + koff);
            }
            #pragma unroll
            for (int rt = 0; rt < 4; ++rt)
                #pragma unroll
                for (int ct = 0; ct < 4; ++ct)
                    Oacc[rt * 4 + ct] = __builtin_amdgcn_mfma_f32_16x16x32_bf16(
                        a[rt], b[ct], Oacc[rt * 4 + ct], 0, 0, 0);
        }
    }

    // -------- epilogue: accumulate M-splits via device-scope fp32 atomics --------
    #pragma unroll
    for (int rt = 0; rt < 4; ++rt) {
        #pragma unroll
        for (int ct = 0; ct < 4; ++ct) {
            f32x4 v = Oacc[rt * 4 + ct];
            const int y = wave * 64 + ct * 16 + l16;
            #pragma unroll
            for (int r = 0; r < 4; ++r) {
                const int row = row0 + rt * 16 + quad * 4 + r;
                atomicAdd(&out[(size_t)row * Y_DIM + y], v[r]);
            }
        }
    }
}

extern "C" void kernel_launch(void* const* d_in, const int* in_sizes, int n_in,
                              void* d_out, int out_size, void* d_ws, size_t ws_size,
                              hipStream_t stream) {
    const float* X = (const float*)d_in[0];
    const float* Z = (const float*)d_in[1];
    const float* W = (const float*)d_in[2];
    const int*  bw = (const int*)d_in[3];
    float* out = (float*)d_out;

    char* ws = (char*)d_ws;
    size_t off = 0;
    unsigned short* Xb  = (unsigned short*)(ws + off); off += (size_t)N_ROWS * D_DIM * 2;
    unsigned short* Zb  = (unsigned short*)(ws + off); off += (size_t)M_PAD * D_DIM * 2;
    unsigned short* WbT = (unsigned short*)(ws + off); off += (size_t)Y_DIM * M_PAD * 2;
    float* xsq = (float*)(ws + off); off += (size_t)N_ROWS * 4;
    float* zsq = (float*)(ws + off); off += (size_t)M_PAD * 4;
    // total ws use: ~68.7 MB

    hipMemsetAsync(d_out, 0, (size_t)out_size * sizeof(float), stream);
    cast_rows_kernel<<<N_ROWS, 256, 0, stream>>>(X, Xb, xsq, N_ROWS);
    cast_rows_kernel<<<M_PAD, 256, 0, stream>>>(Z, Zb, zsq, M_CENT);
    cast_wT_kernel<<<dim3(M_PAD / 32, Y_DIM / 32), 256, 0, stream>>>(W, WbT);
    fused_kernel<<<dim3(N_ROWS / BM, MSPLIT), 256, 0, stream>>>(Xb, Zb, WbT, xsq, zsq, bw, out);
}